// Round 7
// baseline (216.593 us; speedup 1.0000x reference)
//
#include <hip/hip_runtime.h>

// N=4096 nodes, D=512 d_model, H=4 heads.
//
// Math reduction: softmax row-score s[h,i] is constant along the softmax axis
// so it cancels; exp(-1e10)==0 in fp32 and self-loops guarantee deg>=1, so
// attn = adj/deg, head-independent. A_self/A_neigh/LeakyReLU are dead code.
//   out = relu( rownorm(adj) @ (nodes @ Mmat + b_node @ Kbar) ),
//   Mmat = W_node @ Kbar,  Kbar = mean_h K[h].
// R6: aggregate split into scan (streaming CSR build, no barriers) + gather
// (LDS list + unroll-8). R5b's 1024-thr/nt version regressed — reverted.

typedef short  short8 __attribute__((ext_vector_type(8)));
typedef float  f32x4  __attribute__((ext_vector_type(4)));

__device__ inline unsigned short f2bf(float f) {
    union { float f; unsigned int u; } v; v.f = f;
    unsigned int u = v.u;
    u += 0x7fffu + ((u >> 16) & 1u);       // round-nearest-even
    return (unsigned short)(u >> 16);
}

// KbarT[f][d] = bf16( (1/H) * sum_h K[h][d][f] ), via 64x64 LDS transpose tile.
__global__ __launch_bounds__(256) void kbarT_kernel(
        const float* __restrict__ K, unsigned short* __restrict__ KbarT,
        int D, int H, float invH) {
    __shared__ float tile[64][65];
    const int f0 = blockIdx.x * 64, d0 = blockIdx.y * 64;
    const int tid = threadIdx.x;
    const int c4 = (tid & 15) * 4;
    const int DD = D * D;

    for (int rr = tid >> 4; rr < 64; rr += 16) {
        float sx = 0.f, sy = 0.f, sz = 0.f, sw = 0.f;
        for (int h = 0; h < H; ++h) {
            float4 v = *reinterpret_cast<const float4*>(
                &K[(size_t)h * DD + (size_t)(d0 + rr) * D + f0 + c4]);
            sx += v.x; sy += v.y; sz += v.z; sw += v.w;
        }
        tile[rr][c4 + 0] = sx * invH;
        tile[rr][c4 + 1] = sy * invH;
        tile[rr][c4 + 2] = sz * invH;
        tile[rr][c4 + 3] = sw * invH;
    }
    __syncthreads();
    for (int fr = tid >> 4; fr < 64; fr += 16) {
        ushort4 o;
        o.x = f2bf(tile[c4 + 0][fr]);
        o.y = f2bf(tile[c4 + 1][fr]);
        o.z = f2bf(tile[c4 + 2][fr]);
        o.w = f2bf(tile[c4 + 3][fr]);
        *reinterpret_cast<ushort4*>(&KbarT[(size_t)(f0 + fr) * D + d0 + c4]) = o;
    }
}

// Shared MFMA GEMM body: C[m][n] = sum_k A[m][k]*Bt[n][k] (+bias[n]),
// fp32 acc, bf16 out. CA/CB: operand is fp32, converted during LDS staging.
template <bool CA, bool CB>
__device__ inline void gemm_body(const void* __restrict__ Ap,
                                 const void* __restrict__ Btp,
                                 const float* __restrict__ bias,
                                 unsigned short* __restrict__ C,
                                 int Nn, int K, int bx, int by) {
    __shared__ unsigned short As[64][32];
    __shared__ unsigned short Bs[64][32];
    const int tid  = threadIdx.x;
    const int lane = tid & 63;
    const int wave = tid >> 6;
    const int wy = wave >> 1, wx = wave & 1;
    const int row0 = by * 64, col0 = bx * 64;
    const int l15 = lane & 15, quad = lane >> 4;
    const int ldr = tid >> 2;
    const int ldk = (tid & 3) * 8;

    f32x4 acc[2][2] = {};

    for (int k0 = 0; k0 < K; k0 += 32) {
        short8 av, bv;
        if (CA) {
            const float* a = (const float*)Ap + (size_t)(row0 + ldr) * K + k0 + ldk;
            float4 x = *reinterpret_cast<const float4*>(a);
            float4 y = *reinterpret_cast<const float4*>(a + 4);
            av[0] = (short)f2bf(x.x); av[1] = (short)f2bf(x.y);
            av[2] = (short)f2bf(x.z); av[3] = (short)f2bf(x.w);
            av[4] = (short)f2bf(y.x); av[5] = (short)f2bf(y.y);
            av[6] = (short)f2bf(y.z); av[7] = (short)f2bf(y.w);
        } else {
            av = *reinterpret_cast<const short8*>(
                (const unsigned short*)Ap + (size_t)(row0 + ldr) * K + k0 + ldk);
        }
        if (CB) {
            const float* b = (const float*)Btp + (size_t)(col0 + ldr) * K + k0 + ldk;
            float4 x = *reinterpret_cast<const float4*>(b);
            float4 y = *reinterpret_cast<const float4*>(b + 4);
            bv[0] = (short)f2bf(x.x); bv[1] = (short)f2bf(x.y);
            bv[2] = (short)f2bf(x.z); bv[3] = (short)f2bf(x.w);
            bv[4] = (short)f2bf(y.x); bv[5] = (short)f2bf(y.y);
            bv[6] = (short)f2bf(y.z); bv[7] = (short)f2bf(y.w);
        } else {
            bv = *reinterpret_cast<const short8*>(
                (const unsigned short*)Btp + (size_t)(col0 + ldr) * K + k0 + ldk);
        }
        __syncthreads();
        *reinterpret_cast<short8*>(&As[ldr][ldk]) = av;
        *reinterpret_cast<short8*>(&Bs[ldr][ldk]) = bv;
        __syncthreads();
        short8 a0 = *reinterpret_cast<const short8*>(&As[wy * 32 +      l15][quad * 8]);
        short8 a1 = *reinterpret_cast<const short8*>(&As[wy * 32 + 16 + l15][quad * 8]);
        short8 b0 = *reinterpret_cast<const short8*>(&Bs[wx * 32 +      l15][quad * 8]);
        short8 b1 = *reinterpret_cast<const short8*>(&Bs[wx * 32 + 16 + l15][quad * 8]);
        acc[0][0] = __builtin_amdgcn_mfma_f32_16x16x32_bf16(a0, b0, acc[0][0], 0, 0, 0);
        acc[0][1] = __builtin_amdgcn_mfma_f32_16x16x32_bf16(a0, b1, acc[0][1], 0, 0, 0);
        acc[1][0] = __builtin_amdgcn_mfma_f32_16x16x32_bf16(a1, b0, acc[1][0], 0, 0, 0);
        acc[1][1] = __builtin_amdgcn_mfma_f32_16x16x32_bf16(a1, b1, acc[1][1], 0, 0, 0);
    }

    // C/D layout: col = lane&15, row = (lane>>4)*4 + reg  [m89-verified]
#pragma unroll
    for (int mi = 0; mi < 2; ++mi)
#pragma unroll
        for (int ni = 0; ni < 2; ++ni) {
            int col = col0 + wx * 32 + ni * 16 + l15;
            float bvl = bias ? bias[col] : 0.f;
#pragma unroll
            for (int r = 0; r < 4; ++r) {
                int row = row0 + wy * 32 + mi * 16 + quad * 4 + r;
                C[(size_t)row * Nn + col] = f2bf(acc[mi][ni][r] + bvl);
            }
        }
}

// GEMM1 + fused bias2 (extra grid rows do bias2 = b_node @ Kbar, wave per f).
__global__ __launch_bounds__(256) void gemm1_kernel(
        const unsigned short* __restrict__ KbarT, const float* __restrict__ W,
        const float* __restrict__ b, unsigned short* __restrict__ MmatT,
        float* __restrict__ bias2, int D, int gemmY) {
    if ((int)blockIdx.y >= gemmY) {
        int e = ((int)blockIdx.y - gemmY) * gridDim.x + blockIdx.x;
        int wave = threadIdx.x >> 6, lane = threadIdx.x & 63;
        int f = e * 4 + wave;
        if (f >= D) return;
        const unsigned short* kr = KbarT + (size_t)f * D + lane * 8;
        const float* br = b + lane * 8;
        float s = 0.f;
#pragma unroll
        for (int j = 0; j < 8; ++j) {
            union { unsigned int i; float f; } v; v.i = ((unsigned int)kr[j]) << 16;
            s += br[j] * v.f;
        }
#pragma unroll
        for (int off = 32; off; off >>= 1) s += __shfl_down(s, off, 64);
        if (lane == 0) bias2[f] = s;
        return;
    }
    gemm_body<false, true>(KbarT, W, nullptr, MmatT, D, D, blockIdx.x, blockIdx.y);
}

// GEMM2: g[n][f] = sum_d nodes[n][d]*MmatT[f][d] + bias2[f]
__global__ __launch_bounds__(256) void gemm2_kernel(
        const float* __restrict__ nodes, const unsigned short* __restrict__ MmatT,
        const float* __restrict__ bias2, unsigned short* __restrict__ g,
        int D, int K) {
    gemm_body<true, false>(nodes, MmatT, bias2, g, D, K, blockIdx.x, blockIdx.y);
}

// Scan: build per-row CSR. One uint4 (4 adj entries) per thread, pure stream,
// no barriers. adj entries are exactly 0.0f or 1.0f -> test integer bits.
// cnt[] pre-zeroed by hipMemsetAsync. List order arbitrary (sum reassociates).
__global__ __launch_bounds__(256) void scan_kernel(
        const unsigned int* __restrict__ adj_u, int* __restrict__ nbr,
        int* __restrict__ cnt, int N) {
    int idx = blockIdx.x * 256 + threadIdx.x;          // one uint4 per thread
    int q = N >> 2;                                    // uint4 per row
    int row = idx / q;
    int base = (idx - row * q) * 4;
    const uint4 a = reinterpret_cast<const uint4*>(adj_u)[idx];
    int* nrow = nbr + (size_t)row * 1024;
    if (a.x) { int p = atomicAdd(&cnt[row], 1); if (p < 1024) nrow[p] = base;     }
    if (a.y) { int p = atomicAdd(&cnt[row], 1); if (p < 1024) nrow[p] = base + 1; }
    if (a.z) { int p = atomicAdd(&cnt[row], 1); if (p < 1024) nrow[p] = base + 2; }
    if (a.w) { int p = atomicAdd(&cnt[row], 1); if (p < 1024) nrow[p] = base + 3; }
}

// Gather: out[i,:] = relu( (1/deg_i) * sum_{j in nbr[i]} g[j,:] )
// One 256-thread block per row; list staged to LDS (1 barrier), unroll-8
// dword gathers of bf16 g (2 cols/thread). D==512.
__global__ __launch_bounds__(256) void gather_kernel(
        const int* __restrict__ nbr, const int* __restrict__ cnt,
        const unsigned short* __restrict__ g, float* __restrict__ out,
        int N, int D) {
    const int row = blockIdx.x;
    const int tid = threadIdx.x;
    __shared__ int lst[1024];
    int deg = cnt[row]; if (deg > 1024) deg = 1024;
    const int* nrow = nbr + (size_t)row * 1024;
    for (int k = tid; k < deg; k += 256) lst[k] = nrow[k];
    __syncthreads();

    const int col = tid * 2;
    float acc0 = 0.f, acc1 = 0.f;
    int k = 0;
    for (; k + 8 <= deg; k += 8) {
        unsigned int u[8];
#pragma unroll
        for (int j = 0; j < 8; ++j)
            u[j] = *reinterpret_cast<const unsigned int*>(&g[(size_t)lst[k + j] * D + col]);
#pragma unroll
        for (int j = 0; j < 8; ++j) {
            union { unsigned int i; float f; } lo, hi;
            lo.i = u[j] << 16; hi.i = u[j] & 0xffff0000u;
            acc0 += lo.f; acc1 += hi.f;
        }
    }
    for (; k < deg; ++k) {
        unsigned int u = *reinterpret_cast<const unsigned int*>(&g[(size_t)lst[k] * D + col]);
        union { unsigned int i; float f; } lo, hi;
        lo.i = u << 16; hi.i = u & 0xffff0000u;
        acc0 += lo.f; acc1 += hi.f;
    }

    float inv = deg > 0 ? 1.f / (float)deg : 0.f;
    acc0 *= inv; acc1 *= inv;
    float2 o;
    o.x = acc0 > 0.f ? acc0 : 0.f;
    o.y = acc1 > 0.f ? acc1 : 0.f;
    *reinterpret_cast<float2*>(&out[(size_t)row * D + col]) = o;
}

extern "C" void kernel_launch(void* const* d_in, const int* in_sizes, int n_in,
                              void* d_out, int out_size, void* d_ws, size_t ws_size,
                              hipStream_t stream) {
    const float* nodes  = (const float*)d_in[0];
    const float* adj    = (const float*)d_in[1];
    const float* W_node = (const float*)d_in[2];
    const float* b_node = (const float*)d_in[3];
    const float* K      = (const float*)d_in[4];
    // d_in[5] A_self, d_in[6] A_neigh: dead (softmax row-constant cancels).

    const int D  = in_sizes[3];              // 512
    const int N  = in_sizes[0] / D;          // 4096
    const int H  = in_sizes[4] / (D * D);    // 4
    const int DD = D * D;

    float* out = (float*)d_out;

    // ws layout (bytes):
    //   KbarT[DD*2] | MmatT[DD*2] | g[N*D*2] | bias2[D*4] | cnt[N*4] | nbr[N*1024*4]
    char* ws = (char*)d_ws;
    unsigned short* KbarT  = (unsigned short*)(ws);
    unsigned short* MmatT  = (unsigned short*)(ws + (size_t)DD * 2);
    unsigned short* g_bf16 = (unsigned short*)(ws + (size_t)DD * 4);
    float*          bias2  = (float*)        (ws + (size_t)DD * 4 + (size_t)N * D * 2);
    int*            cnt    = (int*)          (ws + (size_t)DD * 4 + (size_t)N * D * 2 + (size_t)D * 4);
    int*            nbr    = (int*)          (ws + (size_t)DD * 4 + (size_t)N * D * 2 + (size_t)D * 4 + (size_t)N * 4);

    // 0. zero the CSR counters (ws is re-poisoned 0xAA before every launch)
    hipMemsetAsync(cnt, 0, (size_t)N * 4, stream);

    // 1. KbarT = transpose(mean_h K), bf16
    {
        dim3 grid(D / 64, D / 64);
        kbarT_kernel<<<grid, 256, 0, stream>>>(K, KbarT, D, H, 1.0f / (float)H);
    }

    // 2. MmatT = (W @ Kbar)^T via MFMA, + fused bias2
    {
        int gx = D / 64, gemmY = D / 64;
        int biasRows = (D / 4 + gx - 1) / gx;
        dim3 grid(gx, gemmY + biasRows);
        gemm1_kernel<<<grid, 256, 0, stream>>>(KbarT, W_node, b_node, MmatT, bias2, D, gemmY);
    }

    // 3. scan adj -> CSR (independent of 2; placed here to keep g hot later)
    scan_kernel<<<(N / 4) * (N / 256), 256, 0, stream>>>(
        (const unsigned int*)adj, nbr, cnt, N);

    // 4. g = nodes @ Mmat + bias2 (MFMA, fp32 A converted during staging)
    {
        dim3 grid(D / 64, N / 64);
        gemm2_kernel<<<grid, 256, 0, stream>>>(nodes, MmatT, bias2, g_bf16, D, D);
    }

    // 5. out = relu(rownorm gather)
    gather_kernel<<<N, 256, 0, stream>>>(nbr, cnt, g_bf16, out, N, D);
}

// Round 8
// 162.076 us; speedup vs baseline: 1.3364x; 1.3364x over previous
//
#include <hip/hip_runtime.h>

// N=4096 nodes, D=512 d_model, H=4 heads.
//
// Math reduction: softmax row-score s[h,i] is constant along the softmax axis
// so it cancels; exp(-1e10)==0 in fp32 and self-loops guarantee deg>=1, so
// attn = adj/deg, head-independent. A_self/A_neigh/LeakyReLU are dead code.
//   out = relu( rownorm(adj) @ (nodes @ Mmat + b_node @ Kbar) ),
//   Mmat = W_node @ Kbar,  Kbar = mean_h K[h].
// R8 = R4 structure (best measured: 160 us). R5b (1024-thr aggregate) and
// R6/R7 (global CSR split: global-atomic latency, 71 us scan) both regressed
// and are reverted. Only change vs R4: gather unroll 8 -> 16.

typedef short  short8 __attribute__((ext_vector_type(8)));
typedef float  f32x4  __attribute__((ext_vector_type(4)));

__device__ inline unsigned short f2bf(float f) {
    union { float f; unsigned int u; } v; v.f = f;
    unsigned int u = v.u;
    u += 0x7fffu + ((u >> 16) & 1u);       // round-nearest-even
    return (unsigned short)(u >> 16);
}

// KbarT[f][d] = bf16( (1/H) * sum_h K[h][d][f] ), via 64x64 LDS transpose tile.
__global__ __launch_bounds__(256) void kbarT_kernel(
        const float* __restrict__ K, unsigned short* __restrict__ KbarT,
        int D, int H, float invH) {
    __shared__ float tile[64][65];
    const int f0 = blockIdx.x * 64, d0 = blockIdx.y * 64;
    const int tid = threadIdx.x;
    const int c4 = (tid & 15) * 4;
    const int DD = D * D;

    for (int rr = tid >> 4; rr < 64; rr += 16) {
        float sx = 0.f, sy = 0.f, sz = 0.f, sw = 0.f;
        for (int h = 0; h < H; ++h) {
            float4 v = *reinterpret_cast<const float4*>(
                &K[(size_t)h * DD + (size_t)(d0 + rr) * D + f0 + c4]);
            sx += v.x; sy += v.y; sz += v.z; sw += v.w;
        }
        tile[rr][c4 + 0] = sx * invH;
        tile[rr][c4 + 1] = sy * invH;
        tile[rr][c4 + 2] = sz * invH;
        tile[rr][c4 + 3] = sw * invH;
    }
    __syncthreads();
    for (int fr = tid >> 4; fr < 64; fr += 16) {
        ushort4 o;
        o.x = f2bf(tile[c4 + 0][fr]);
        o.y = f2bf(tile[c4 + 1][fr]);
        o.z = f2bf(tile[c4 + 2][fr]);
        o.w = f2bf(tile[c4 + 3][fr]);
        *reinterpret_cast<ushort4*>(&KbarT[(size_t)(f0 + fr) * D + d0 + c4]) = o;
    }
}

// Shared MFMA GEMM body: C[m][n] = sum_k A[m][k]*Bt[n][k] (+bias[n]),
// fp32 acc, bf16 out. CA/CB: operand is fp32, converted during LDS staging.
template <bool CA, bool CB>
__device__ inline void gemm_body(const void* __restrict__ Ap,
                                 const void* __restrict__ Btp,
                                 const float* __restrict__ bias,
                                 unsigned short* __restrict__ C,
                                 int Nn, int K, int bx, int by) {
    __shared__ unsigned short As[64][32];
    __shared__ unsigned short Bs[64][32];
    const int tid  = threadIdx.x;
    const int lane = tid & 63;
    const int wave = tid >> 6;
    const int wy = wave >> 1, wx = wave & 1;
    const int row0 = by * 64, col0 = bx * 64;
    const int l15 = lane & 15, quad = lane >> 4;
    const int ldr = tid >> 2;
    const int ldk = (tid & 3) * 8;

    f32x4 acc[2][2] = {};

    for (int k0 = 0; k0 < K; k0 += 32) {
        short8 av, bv;
        if (CA) {
            const float* a = (const float*)Ap + (size_t)(row0 + ldr) * K + k0 + ldk;
            float4 x = *reinterpret_cast<const float4*>(a);
            float4 y = *reinterpret_cast<const float4*>(a + 4);
            av[0] = (short)f2bf(x.x); av[1] = (short)f2bf(x.y);
            av[2] = (short)f2bf(x.z); av[3] = (short)f2bf(x.w);
            av[4] = (short)f2bf(y.x); av[5] = (short)f2bf(y.y);
            av[6] = (short)f2bf(y.z); av[7] = (short)f2bf(y.w);
        } else {
            av = *reinterpret_cast<const short8*>(
                (const unsigned short*)Ap + (size_t)(row0 + ldr) * K + k0 + ldk);
        }
        if (CB) {
            const float* b = (const float*)Btp + (size_t)(col0 + ldr) * K + k0 + ldk;
            float4 x = *reinterpret_cast<const float4*>(b);
            float4 y = *reinterpret_cast<const float4*>(b + 4);
            bv[0] = (short)f2bf(x.x); bv[1] = (short)f2bf(x.y);
            bv[2] = (short)f2bf(x.z); bv[3] = (short)f2bf(x.w);
            bv[4] = (short)f2bf(y.x); bv[5] = (short)f2bf(y.y);
            bv[6] = (short)f2bf(y.z); bv[7] = (short)f2bf(y.w);
        } else {
            bv = *reinterpret_cast<const short8*>(
                (const unsigned short*)Btp + (size_t)(col0 + ldr) * K + k0 + ldk);
        }
        __syncthreads();
        *reinterpret_cast<short8*>(&As[ldr][ldk]) = av;
        *reinterpret_cast<short8*>(&Bs[ldr][ldk]) = bv;
        __syncthreads();
        short8 a0 = *reinterpret_cast<const short8*>(&As[wy * 32 +      l15][quad * 8]);
        short8 a1 = *reinterpret_cast<const short8*>(&As[wy * 32 + 16 + l15][quad * 8]);
        short8 b0 = *reinterpret_cast<const short8*>(&Bs[wx * 32 +      l15][quad * 8]);
        short8 b1 = *reinterpret_cast<const short8*>(&Bs[wx * 32 + 16 + l15][quad * 8]);
        acc[0][0] = __builtin_amdgcn_mfma_f32_16x16x32_bf16(a0, b0, acc[0][0], 0, 0, 0);
        acc[0][1] = __builtin_amdgcn_mfma_f32_16x16x32_bf16(a0, b1, acc[0][1], 0, 0, 0);
        acc[1][0] = __builtin_amdgcn_mfma_f32_16x16x32_bf16(a1, b0, acc[1][0], 0, 0, 0);
        acc[1][1] = __builtin_amdgcn_mfma_f32_16x16x32_bf16(a1, b1, acc[1][1], 0, 0, 0);
    }

    // C/D layout: col = lane&15, row = (lane>>4)*4 + reg  [m89-verified]
#pragma unroll
    for (int mi = 0; mi < 2; ++mi)
#pragma unroll
        for (int ni = 0; ni < 2; ++ni) {
            int col = col0 + wx * 32 + ni * 16 + l15;
            float bvl = bias ? bias[col] : 0.f;
#pragma unroll
            for (int r = 0; r < 4; ++r) {
                int row = row0 + wy * 32 + mi * 16 + quad * 4 + r;
                C[(size_t)row * Nn + col] = f2bf(acc[mi][ni][r] + bvl);
            }
        }
}

// GEMM1 + fused bias2 (extra grid rows do bias2 = b_node @ Kbar, wave per f).
__global__ __launch_bounds__(256) void gemm1_kernel(
        const unsigned short* __restrict__ KbarT, const float* __restrict__ W,
        const float* __restrict__ b, unsigned short* __restrict__ MmatT,
        float* __restrict__ bias2, int D, int gemmY) {
    if ((int)blockIdx.y >= gemmY) {
        int e = ((int)blockIdx.y - gemmY) * gridDim.x + blockIdx.x;
        int wave = threadIdx.x >> 6, lane = threadIdx.x & 63;
        int f = e * 4 + wave;
        if (f >= D) return;
        const unsigned short* kr = KbarT + (size_t)f * D + lane * 8;
        const float* br = b + lane * 8;
        float s = 0.f;
#pragma unroll
        for (int j = 0; j < 8; ++j) {
            union { unsigned int i; float f; } v; v.i = ((unsigned int)kr[j]) << 16;
            s += br[j] * v.f;
        }
#pragma unroll
        for (int off = 32; off; off >>= 1) s += __shfl_down(s, off, 64);
        if (lane == 0) bias2[f] = s;
        return;
    }
    gemm_body<false, true>(KbarT, W, nullptr, MmatT, D, D, blockIdx.x, blockIdx.y);
}

// GEMM2: g[n][f] = sum_d nodes[n][d]*MmatT[f][d] + bias2[f]
__global__ __launch_bounds__(256) void gemm2_kernel(
        const float* __restrict__ nodes, const unsigned short* __restrict__ MmatT,
        const float* __restrict__ bias2, unsigned short* __restrict__ g,
        int D, int K) {
    gemm_body<true, false>(nodes, MmatT, bias2, g, D, K, blockIdx.x, blockIdx.y);
}

// out[i,:] = relu( (1/deg_i) * sum_{j: adj[i,j]=1} g[j,:] )
// One 256-thread block per row. Phase 1: one-pass LDS neighbor-list build
// (LDS atomics, single barrier — measured better than both the 1024-thr
// variant (R5b) and the global-CSR split (R7)). Phase 2: unroll-16 gather
// of bf16 g rows (64 B in flight/thread). Assumes N%1024==0, D==512.
__global__ __launch_bounds__(256) void aggregate_kernel(
        const float* __restrict__ adj, const unsigned short* __restrict__ g,
        float* __restrict__ out, int N, int D) {
    const int row = blockIdx.x;
    const int tid = threadIdx.x;
    __shared__ int lst[1024];
    __shared__ int cnt;
    if (tid == 0) cnt = 0;
    __syncthreads();

    const float* arow = adj + (size_t)row * N;
    const int nper = N >> 8;            // elems per thread (16 @ N=4096)
    const int base = tid * nper;
    const float4* ap = reinterpret_cast<const float4*>(arow + base);
    for (int c = 0; c < (nper >> 2); ++c) {
        float4 a = ap[c];
        int b4 = base + c * 4;
        if (a.x > 0.5f) { int p = atomicAdd(&cnt, 1); if (p < 1024) lst[p] = b4;     }
        if (a.y > 0.5f) { int p = atomicAdd(&cnt, 1); if (p < 1024) lst[p] = b4 + 1; }
        if (a.z > 0.5f) { int p = atomicAdd(&cnt, 1); if (p < 1024) lst[p] = b4 + 2; }
        if (a.w > 0.5f) { int p = atomicAdd(&cnt, 1); if (p < 1024) lst[p] = b4 + 3; }
    }
    __syncthreads();
    int deg = cnt; if (deg > 1024) deg = 1024;

    const int col = tid * 2;
    float acc0 = 0.f, acc1 = 0.f;
    int k = 0;
    for (; k + 16 <= deg; k += 16) {
        unsigned int u[16];
#pragma unroll
        for (int j = 0; j < 16; ++j)
            u[j] = *reinterpret_cast<const unsigned int*>(&g[(size_t)lst[k + j] * D + col]);
#pragma unroll
        for (int j = 0; j < 16; ++j) {
            union { unsigned int i; float f; } lo, hi;
            lo.i = u[j] << 16; hi.i = u[j] & 0xffff0000u;
            acc0 += lo.f; acc1 += hi.f;
        }
    }
    for (; k < deg; ++k) {
        unsigned int u = *reinterpret_cast<const unsigned int*>(&g[(size_t)lst[k] * D + col]);
        union { unsigned int i; float f; } lo, hi;
        lo.i = u << 16; hi.i = u & 0xffff0000u;
        acc0 += lo.f; acc1 += hi.f;
    }

    float inv = deg > 0 ? 1.f / (float)deg : 0.f;
    acc0 *= inv; acc1 *= inv;
    float2 o;
    o.x = acc0 > 0.f ? acc0 : 0.f;
    o.y = acc1 > 0.f ? acc1 : 0.f;
    *reinterpret_cast<float2*>(&out[(size_t)row * D + col]) = o;
}

extern "C" void kernel_launch(void* const* d_in, const int* in_sizes, int n_in,
                              void* d_out, int out_size, void* d_ws, size_t ws_size,
                              hipStream_t stream) {
    const float* nodes  = (const float*)d_in[0];
    const float* adj    = (const float*)d_in[1];
    const float* W_node = (const float*)d_in[2];
    const float* b_node = (const float*)d_in[3];
    const float* K      = (const float*)d_in[4];
    // d_in[5] A_self, d_in[6] A_neigh: dead (softmax row-constant cancels).

    const int D  = in_sizes[3];              // 512
    const int N  = in_sizes[0] / D;          // 4096
    const int H  = in_sizes[4] / (D * D);    // 4
    const int DD = D * D;

    float* out = (float*)d_out;

    // ws layout (bytes): KbarT[DD*2] | MmatT[DD*2] | g[N*D*2] | bias2[D*4]
    char* ws = (char*)d_ws;
    unsigned short* KbarT  = (unsigned short*)(ws);
    unsigned short* MmatT  = (unsigned short*)(ws + (size_t)DD * 2);
    unsigned short* g_bf16 = (unsigned short*)(ws + (size_t)DD * 4);
    float*          bias2  = (float*)        (ws + (size_t)DD * 4 + (size_t)N * D * 2);

    // 1. KbarT = transpose(mean_h K), bf16
    {
        dim3 grid(D / 64, D / 64);
        kbarT_kernel<<<grid, 256, 0, stream>>>(K, KbarT, D, H, 1.0f / (float)H);
    }

    // 2. MmatT = (W @ Kbar)^T via MFMA, + fused bias2
    {
        int gx = D / 64, gemmY = D / 64;
        int biasRows = (D / 4 + gx - 1) / gx;
        dim3 grid(gx, gemmY + biasRows);
        gemm1_kernel<<<grid, 256, 0, stream>>>(KbarT, W_node, b_node, MmatT, bias2, D, gemmY);
    }

    // 3. g = nodes @ Mmat + bias2 (MFMA, fp32 A converted during staging)
    {
        dim3 grid(D / 64, N / 64);
        gemm2_kernel<<<grid, 256, 0, stream>>>(nodes, MmatT, bias2, g_bf16, D, D);
    }

    // 4. out = relu(rownorm(adj) @ g)
    aggregate_kernel<<<N, 256, 0, stream>>>(adj, g_bf16, out, N, D);
}